// Round 2
// baseline (141.327 us; speedup 1.0000x reference)
//
#include <hip/hip_runtime.h>

// image (1,1024,1024) f32, x (16,1,1024,1024) f32, W_KL (9,1,3,3) f32, b_KL (9,) f32.
// y[b,h,w] = sum_{a,d} (conv(image,W_KL)[a*3+d][h,w] + b[a*3+d]) * x[b,h+a-1,w+d-1]
#define IH 1024
#define IW 1024
#define NB 16
#define BPB 4   // batches per block (gridDim.z = NB/BPB)

typedef float v4f __attribute__((ext_vector_type(4)));

// Raw (un-finalized) 3x6 window for 4 px at (h, w0..w0+3): per row a, the
// aligned core v4f [w0..w0+3] plus scalar halo dwords at w0-1 and w0+4.
// Row indices are CLAMPED in-bounds (garbage data for padded rows is later
// multiplied by a zeroed Kv coefficient, contributing exactly 0).
// 18 VGPRs per window.
struct RawWin { v4f mv[3]; float fl[3]; float fr[3]; };

__device__ __forceinline__ void issue_win(const float* __restrict__ plane,
                                          int h, int w0, RawWin& rw) {
#pragma unroll
    for (int a = 0; a < 3; ++a) {
        const int hh = h + a - 1;
        const int hc = (hh < 0) ? 0 : (hh >= IH ? IH - 1 : hh);
        const float* rowp = plane + (size_t)hc * IW;
        rw.fl[a] = rowp[w0 > 0 ? w0 - 1 : 0];            // dword, 4B-aligned is enough
        rw.mv[a] = *(const v4f*)(rowp + w0);
        rw.fr[a] = rowp[w0 + 4 < IW ? w0 + 4 : IW - 1];
    }
}

// x-window finalize: only the per-lane w-halo selects; row validity is
// handled by Kv row-masking (cheaper: once per thread, not per batch).
__device__ __forceinline__ void fin_win_x(const RawWin& rw, int w0, float win[3][6]) {
#pragma unroll
    for (int a = 0; a < 3; ++a) {
        win[a][0] = (w0 > 0)      ? rw.fl[a]   : 0.f;
        win[a][1] = rw.mv[a].x;
        win[a][2] = rw.mv[a].y;
        win[a][3] = rw.mv[a].z;
        win[a][4] = rw.mv[a].w;
        win[a][5] = (w0 + 4 < IW) ? rw.fr[a]   : 0.f;
    }
}

// image-window finalize: full zero-pad masking (feeds the conv directly).
__device__ __forceinline__ void fin_win_img(const RawWin& rw, int h, int w0,
                                            float win[3][6]) {
#pragma unroll
    for (int a = 0; a < 3; ++a) {
        const int hh = h + a - 1;
        const bool rowok = (hh >= 0) & (hh < IH);
        win[a][0] = (rowok && w0 > 0)      ? rw.fl[a]   : 0.f;
        win[a][1] = rowok ? rw.mv[a].x : 0.f;
        win[a][2] = rowok ? rw.mv[a].y : 0.f;
        win[a][3] = rowok ? rw.mv[a].z : 0.f;
        win[a][4] = rowok ? rw.mv[a].w : 0.f;
        win[a][5] = (rowok && w0 + 4 < IW) ? rw.fr[a]   : 0.f;
    }
}

// Block 64x4 = 256 thr; thread: 4 px at (h, w0..w0+3), BPB batches.
// ALL 45 loads (image window + BPB x-windows) are issued up front in
// consumption order, then pinned above the compute with sched_barrier(0)
// so the register allocator cannot sink them (round-1 failure: VGPR=52
// proved the compiler serialized the pipeline). Compute then proceeds on
// counted vmcnt waits: K-phase waits vmcnt(36), batch i waits vmcnt(27-9i).
__global__ __launch_bounds__(256) void fused_smblock(
    const float* __restrict__ image,
    const float* __restrict__ x,
    const float* __restrict__ Wk,
    const float* __restrict__ bk,
    float* __restrict__ out)
{
    const int tx = threadIdx.x;               // 0..63 (one wave per ty)
    const int ty = threadIdx.y;               // 0..3
    const int w0 = blockIdx.x * 256 + tx * 4; // float4-aligned
    const int h  = blockIdx.y * 4 + ty;
    const int b0 = blockIdx.z * BPB;

    // conv weights / bias: uniform addresses -> scalar loads (SGPRs)
    float wk[81];
#pragma unroll
    for (int i = 0; i < 81; ++i) wk[i] = Wk[i];
    float bb[9];
#pragma unroll
    for (int c = 0; c < 9; ++c) bb[c] = bk[c];

    const size_t plane = (size_t)IH * IW;
    const float* __restrict__ xb = x + (size_t)b0 * plane;

    // ---- load cluster: 9 image loads, then 9 loads per batch, in order ----
    RawWin rimg;
    issue_win(image, h, w0, rimg);
    RawWin rx[BPB];
#pragma unroll
    for (int i = 0; i < BPB; ++i)
        issue_win(xb + (size_t)i * plane, h, w0, rx[i]);
    __builtin_amdgcn_sched_barrier(0);        // loads stay above; compute below

    // ---- K phase: per-pixel kernels from image (waits vmcnt(36)) ----
    float p[3][6];
    fin_win_img(rimg, h, w0, p);
    float Kv[4][9];
#pragma unroll
    for (int j = 0; j < 4; ++j)
#pragma unroll
        for (int c = 0; c < 9; ++c) {
            float acc = bb[c];
#pragma unroll
            for (int a = 0; a < 3; ++a)
#pragma unroll
                for (int d = 0; d < 3; ++d)
                    acc = fmaf(wk[c * 9 + a * 3 + d], p[a][j + d], acc);
            Kv[j][c] = acc;
        }

    // Row-pad masking for the APPLY step, folded into Kv (once per thread):
    // x_pad row h-1 (h==0) / h+1 (h==IH-1) is zero -> zero those 3 taps.
    {
        const bool top = (h == 0);
        const bool bot = (h == IH - 1);
#pragma unroll
        for (int j = 0; j < 4; ++j)
#pragma unroll
            for (int d = 0; d < 3; ++d) {
                Kv[j][d]     = top ? 0.f : Kv[j][d];
                Kv[j][6 + d] = bot ? 0.f : Kv[j][6 + d];
            }
    }

    // ---- apply phase: batch i waits vmcnt((BPB-1-i)*9), later loads stay in flight ----
    float* __restrict__ ob = out + (size_t)b0 * plane + (size_t)h * IW + w0;
#pragma unroll
    for (int i = 0; i < BPB; ++i) {
        float win[3][6];
        fin_win_x(rx[i], w0, win);
        v4f y;
#pragma unroll
        for (int j = 0; j < 4; ++j) {
            float acc = 0.f;
#pragma unroll
            for (int a = 0; a < 3; ++a)
#pragma unroll
                for (int d = 0; d < 3; ++d)
                    acc = fmaf(Kv[j][a * 3 + d], win[a][j + d], acc);
            y[j] = acc;
        }
        __builtin_nontemporal_store(y, (v4f*)(ob + (size_t)i * plane));
    }
}

extern "C" void kernel_launch(void* const* d_in, const int* in_sizes, int n_in,
                              void* d_out, int out_size, void* d_ws, size_t ws_size,
                              hipStream_t stream) {
    const float* image = (const float*)d_in[0]; // 1*1024*1024
    const float* x     = (const float*)d_in[1]; // 16*1*1024*1024
    const float* Wk    = (const float*)d_in[2]; // 9*1*3*3
    const float* bk    = (const float*)d_in[3]; // 9
    float* out = (float*)d_out;                 // 16*1024*1024 f32

    dim3 block(64, 4);
    dim3 grid(IW / 256, IH / 4, NB / BPB);      // (4, 256, 4) = 4096 blocks
    fused_smblock<<<grid, block, 0, stream>>>(image, x, Wk, bk, out);
}